// Round 1
// baseline (432.959 us; speedup 1.0000x reference)
//
#include <hip/hip_runtime.h>
#include <stdint.h>

#define DD 160
#define HH 160
#define WW 160
#define NGRID (DD*HH*WW)
#define CIN 32
#define COUT 64
#define KK 27
#define NQ 8            // CIN/4 packed quads
#define BLOCK 1024
#define WPB 16          // waves per block
#define NBLOCKS 256

__device__ __forceinline__ uint32_t f2bf(float f) {
    uint32_t u = __float_as_uint(f);
    return (u + 0x7fffu + ((u >> 16) & 1u)) >> 16;   // RNE, inputs are finite
}
__device__ __forceinline__ float blo(uint32_t u) { return __uint_as_float(u << 16); }
__device__ __forceinline__ float bhi(uint32_t u) { return __uint_as_float(u & 0xffff0000u); }

__global__ void scatter_grid(const int* __restrict__ coors, int* __restrict__ grid, int n) {
    int i = blockIdx.x * 256 + threadIdx.x;
    if (i < n) {
        int z = coors[i*4+1], y = coors[i*4+2], x = coors[i*4+3];
        grid[(z*HH + y)*WW + x] = i;
    }
}

// weight f32 [k][ci][co] -> packed bf16 uint2 [k][q][co]  (q = ci/4)
__global__ void pack_weights(const float* __restrict__ w, uint2* __restrict__ wpk) {
    int t = blockIdx.x * 256 + threadIdx.x;
    if (t >= KK*NQ*COUT) return;
    int co = t & 63;
    int q  = (t >> 6) & 7;
    int k  = t >> 9;
    const float* base = w + (size_t)k*CIN*COUT + co;
    float w0 = base[(4*q+0)*COUT];
    float w1 = base[(4*q+1)*COUT];
    float w2 = base[(4*q+2)*COUT];
    float w3 = base[(4*q+3)*COUT];
    uint2 r;
    r.x = f2bf(w0) | (f2bf(w1) << 16);
    r.y = f2bf(w2) | (f2bf(w3) << 16);
    wpk[t] = r;
}

// one wave per voxel; lane = c_out; lanes 0..26 probe neighbors
__global__ __launch_bounds__(BLOCK, 4) void sparse_conv(
    const float* __restrict__ feats, const int* __restrict__ coors,
    const float* __restrict__ bias, const uint2* __restrict__ wpk,
    const int* __restrict__ grid, float* __restrict__ out, int n)
{
    extern __shared__ uint2 wlds[];   // [KK*NQ*COUT] = 110,592 B

    for (int t = threadIdx.x; t < KK*NQ*COUT; t += BLOCK)
        wlds[t] = wpk[t];
    __syncthreads();

    const int lane = threadIdx.x & 63;
    const int wave = __builtin_amdgcn_readfirstlane((int)(threadIdx.x >> 6));
    const int stride = gridDim.x * WPB;

    const float b = bias[lane];

    // neighbor offset for this lane (lanes 0..26)
    const int dz = lane / 9 - 1;
    const int dy = (lane / 3) % 3 - 1;
    const int dx = lane % 3 - 1;

    for (int v = blockIdx.x * WPB + wave; v < n; v += stride) {
        const int z = coors[v*4+1];
        const int y = coors[v*4+2];
        const int x = coors[v*4+3];

        int nidx = -1;
        if (lane < KK) {
            int nz = z + dz, ny = y + dy, nx = x + dx;
            if (nz >= 0 && nz < DD && ny >= 0 && ny < HH && nx >= 0 && nx < WW)
                nidx = grid[(nz*HH + ny)*WW + nx];
        }
        unsigned long long m = __ballot(nidx >= 0);

        float a0 = 0.f, a1 = 0.f, a2 = 0.f, a3 = 0.f;

        while (m) {
            const int k = __ffsll(m) - 1;
            m &= (m - 1);
            const int j = __builtin_amdgcn_readlane(nidx, k);   // wave-uniform -> SGPR

            const float4* fp = (const float4*)(feats + (size_t)j * CIN);
            float4 f[NQ];
            #pragma unroll
            for (int q = 0; q < NQ; ++q) f[q] = fp[q];

            const uint2* wl = wlds + (size_t)k * NQ * COUT + lane;
            #pragma unroll
            for (int q = 0; q < NQ; ++q) {
                uint2 wq = wl[q * COUT];
                a0 = fmaf(f[q].x, blo(wq.x), a0);
                a1 = fmaf(f[q].y, bhi(wq.x), a1);
                a2 = fmaf(f[q].z, blo(wq.y), a2);
                a3 = fmaf(f[q].w, bhi(wq.y), a3);
            }
        }

        out[(size_t)v * COUT + lane] = b + a0 + a1 + a2 + a3;
    }
}

extern "C" void kernel_launch(void* const* d_in, const int* in_sizes, int n_in,
                              void* d_out, int out_size, void* d_ws, size_t ws_size,
                              hipStream_t stream) {
    const float* feats  = (const float*)d_in[0];
    const int*   coors  = (const int*)d_in[1];
    const float* weight = (const float*)d_in[2];
    const float* bias   = (const float*)d_in[3];
    float*       outp   = (float*)d_out;

    const int n = in_sizes[1] / 4;   // 400000

    int*   grid = (int*)d_ws;
    uint2* wpk  = (uint2*)((char*)d_ws + (size_t)NGRID * sizeof(int));

    // dense index grid: fill with -1 (0xFF bytes), then scatter voxel ids
    hipMemsetAsync(grid, 0xFF, (size_t)NGRID * sizeof(int), stream);
    scatter_grid<<<(n + 255) / 256, 256, 0, stream>>>(coors, grid, n);

    pack_weights<<<(KK*NQ*COUT + 255) / 256, 256, 0, stream>>>(weight, wpk);

    const size_t lds = (size_t)KK * NQ * COUT * sizeof(uint2);  // 110,592 B
    sparse_conv<<<NBLOCKS, BLOCK, lds, stream>>>(feats, coors, bias, wpk, grid, outp, n);
}